// Round 1
// baseline (450.936 us; speedup 1.0000x reference)
//
#include <hip/hip_runtime.h>

#define S_LEN 4096
#define DIM 64
#define NHEAD 64        // B*H = 4*16
#define NCHUNK 8
#define CHUNK (S_LEN / NCHUNK)   // 512
#define LDK 68          // padded leading dim for LDS tiles (16B-aligned rows)
#define PHEAD 4160      // 65*64 floats per head: rows e=0..63 are KV^T, row 64 = Ksum

__device__ __forceinline__ float elu1(float x) {
    // elu(x)+1 : x>0 -> x+1 ; x<=0 -> exp(x)
    return x > 0.0f ? x + 1.0f : __expf(x);
}

// ---------------- pass 1: partial KV (64x64) + Ksum per (head, chunk) ----------------
__global__ __launch_bounds__(256) void pass1_kv(
    const float* __restrict__ K, const float* __restrict__ V,
    const float* __restrict__ mask, float* __restrict__ partials)
{
    const int head  = blockIdx.x / NCHUNK;
    const int chunk = blockIdx.x % NCHUNK;
    const int t  = threadIdx.x;
    const int tx = t & 15;        // e-group
    const int ty = t >> 4;        // d-group
    const int e0 = tx * 4;
    const int d0 = ty * 4;

    __shared__ float kf[64 * LDK];
    __shared__ float vf[64 * LDK];

    float acc[4][4] = {{0.f,0.f,0.f,0.f},{0.f,0.f,0.f,0.f},{0.f,0.f,0.f,0.f},{0.f,0.f,0.f,0.f}};
    float ks[4] = {0.f, 0.f, 0.f, 0.f};

    const long hbase = (long)head * S_LEN * DIM;

    for (int tile = 0; tile < CHUNK / 64; ++tile) {
        const int sbase = chunk * CHUNK + tile * 64;
        __syncthreads();   // protect LDS reads of previous tile
        // stage 64 rows x 64 cols of K (featurized+masked) and V: 1024 float4, 4 per thread
        #pragma unroll
        for (int i = 0; i < 4; ++i) {
            const int v4  = i * 256 + t;
            const int row = v4 >> 4;
            const int col = (v4 & 15) * 4;
            const float4 kq = *(const float4*)(K + hbase + (long)(sbase + row) * DIM + col);
            const float4 vq = *(const float4*)(V + hbase + (long)(sbase + row) * DIM + col);
            const float m = mask[head * S_LEN + sbase + row];
            float4 ko;
            ko.x = elu1(kq.x) * m; ko.y = elu1(kq.y) * m;
            ko.z = elu1(kq.z) * m; ko.w = elu1(kq.w) * m;
            *(float4*)&kf[row * LDK + col] = ko;
            *(float4*)&vf[row * LDK + col] = vq;
        }
        __syncthreads();
        #pragma unroll 4
        for (int s = 0; s < 64; ++s) {
            const float4 kk = *(const float4*)&kf[s * LDK + d0];
            const float4 vv = *(const float4*)&vf[s * LDK + e0];
            acc[0][0] += kk.x * vv.x; acc[0][1] += kk.x * vv.y; acc[0][2] += kk.x * vv.z; acc[0][3] += kk.x * vv.w;
            acc[1][0] += kk.y * vv.x; acc[1][1] += kk.y * vv.y; acc[1][2] += kk.y * vv.z; acc[1][3] += kk.y * vv.w;
            acc[2][0] += kk.z * vv.x; acc[2][1] += kk.z * vv.y; acc[2][2] += kk.z * vv.z; acc[2][3] += kk.z * vv.w;
            acc[3][0] += kk.w * vv.x; acc[3][1] += kk.w * vv.y; acc[3][2] += kk.w * vv.z; acc[3][3] += kk.w * vv.w;
            if (tx == 0) { ks[0] += kk.x; ks[1] += kk.y; ks[2] += kk.z; ks[3] += kk.w; }
        }
    }

    // store partial, transposed layout: P[e][d]  (e-major) so pass2 can s_load rows
    float* P = partials + (long)(head * NCHUNK + chunk) * PHEAD;
    #pragma unroll
    for (int ei = 0; ei < 4; ++ei) {
        float4 w = make_float4(acc[0][ei], acc[1][ei], acc[2][ei], acc[3][ei]);
        *(float4*)(P + (e0 + ei) * 64 + d0) = w;
    }
    if (tx == 0) {
        *(float4*)(P + 64 * 64 + d0) = make_float4(ks[0], ks[1], ks[2], ks[3]);
    }
}

// ---------------- reduce: sum NCHUNK partials -> final KV^T (+Ksum) per head ----------------
__global__ __launch_bounds__(256) void reduce_kv(
    const float* __restrict__ partials, float* __restrict__ kvf)
{
    const int head = blockIdx.x;
    for (int idx = threadIdx.x; idx < PHEAD; idx += 256) {
        float s = 0.f;
        #pragma unroll
        for (int c = 0; c < NCHUNK; ++c)
            s += partials[(long)(head * NCHUNK + c) * PHEAD + idx];
        kvf[(long)head * PHEAD + idx] = s;
    }
}

// ---------------- pass 2: out = (Qf @ KV) / (Qf . Ksum) ----------------
// lane-per-row: each lane holds one Qf row in 64 VGPRs; KV^T rows are wave-uniform
// (scalar loads). 4 waves/block share one 64-row tile, splitting the e range 16 each.
__global__ __launch_bounds__(256) void pass2_out(
    const float* __restrict__ Q, const float* __restrict__ kvf,
    float* __restrict__ out)
{
    const int head  = blockIdx.x >> 6;
    const int tile  = blockIdx.x & 63;
    const int sbase = tile * 64;
    const int t    = threadIdx.x;
    const int lane = t & 63;
    const int wave = t >> 6;

    __shared__ float qt[64 * LDK];   // staged Qf tile (padded)
    __shared__ float ot[64 * 64];    // output tile, XOR/rotate swizzled

    const long hbase = (long)head * S_LEN * DIM;

    // stage Q tile with elu+1 applied
    #pragma unroll
    for (int i = 0; i < 4; ++i) {
        const int v4  = i * 256 + t;
        const int row = v4 >> 4;
        const int col = (v4 & 15) * 4;
        const float4 qv = *(const float4*)(Q + hbase + (long)(sbase + row) * DIM + col);
        float4 qo;
        qo.x = elu1(qv.x); qo.y = elu1(qv.y); qo.z = elu1(qv.z); qo.w = elu1(qv.w);
        *(float4*)&qt[row * LDK + col] = qo;
    }
    __syncthreads();

    // each lane pulls its entire row into registers
    float q[64];
    #pragma unroll
    for (int i = 0; i < 16; ++i) {
        const float4 v = *(const float4*)&qt[lane * LDK + i * 4];
        q[i * 4 + 0] = v.x; q[i * 4 + 1] = v.y; q[i * 4 + 2] = v.z; q[i * 4 + 3] = v.w;
    }

    const float* __restrict__ kvt = kvf + (long)head * PHEAD;

    // denominator: Qf . Ksum  (row 64 of kvt) — wave-uniform loads
    float denom = 0.f;
    #pragma unroll
    for (int d = 0; d < 64; ++d) denom += q[d] * kvt[64 * 64 + d];
    const float rz = 1.0f / denom;

    // each wave handles 16 output columns
    for (int e = wave * 16; e < wave * 16 + 16; ++e) {
        float acc = 0.f;
        #pragma unroll
        for (int d = 0; d < 64; ++d) acc += q[d] * kvt[e * 64 + d];
        ot[lane * 64 + ((e + lane) & 63)] = acc * rz;   // rotate-swizzle: conflict-free
    }
    __syncthreads();

    // coalesced store: 256 threads cover the 64x64 tile
    #pragma unroll
    for (int i = 0; i < 16; ++i) {
        const int row = i * 4 + wave;
        const int col = lane;
        out[hbase + (long)(sbase + row) * DIM + col] = ot[row * 64 + ((col + row) & 63)];
    }
}

extern "C" void kernel_launch(void* const* d_in, const int* in_sizes, int n_in,
                              void* d_out, int out_size, void* d_ws, size_t ws_size,
                              hipStream_t stream) {
    const float* Q    = (const float*)d_in[0];
    const float* K    = (const float*)d_in[1];
    const float* V    = (const float*)d_in[2];
    const float* mask = (const float*)d_in[3];
    float* out = (float*)d_out;

    float* partials = (float*)d_ws;                           // 64*8*4160 floats ≈ 8.5 MB
    float* kvf = partials + (long)NHEAD * NCHUNK * PHEAD;     // 64*4160 floats ≈ 1.1 MB

    pass1_kv<<<NHEAD * NCHUNK, 256, 0, stream>>>(K, V, mask, partials);
    reduce_kv<<<NHEAD, 256, 0, stream>>>(partials, kvf);
    pass2_out<<<NHEAD * 64, 256, 0, stream>>>(Q, kvf, out);
}